// Round 5
// baseline (1093.665 us; speedup 1.0000x reference)
//
#include <hip/hip_runtime.h>
#include <hip/hip_bf16.h>
#include <stdint.h>

#define M_ROWS 300000

typedef __attribute__((ext_vector_type(8)))  short bf16x8;
typedef __attribute__((ext_vector_type(16))) float f32x16;

union U4 { uint4 u; bf16x8 h; unsigned short us[8]; };

__device__ __forceinline__ unsigned short f2bf(float f) {
  union { float f; uint32_t u; } v; v.f = f;
  uint32_t r = v.u + 0x7fffu + ((v.u >> 16) & 1u);
  return (unsigned short)(r >> 16);
}

// ---- packed weight tile table (tiles of 32 cols x 16 k, 1 KiB each) ----
#define T_SP 0
#define T_ST 64
#define T_P1 128
#define T_P2 256
#define T_R1 272
#define T_R2 400
#define T_S1 416
#define T_S2 544
#define T_W1 576
#define T_W2 704
#define T_M1 720
#define T_M2 848
#define T_TOT 864

__global__ void prep_w(const float* Wsp, const float* Wst, const float* Wp1, const float* Wp2,
                       const float* Wr1, const float* Wr2, const float* Ws1, const float* Ws2,
                       const float* Ww1, const float* Ww2, const float* Wm1, const float* Wm2,
                       uint4* ws) {
  int b = blockIdx.x, l = threadIdx.x;
  const int starts[12] = {T_SP,T_ST,T_P1,T_P2,T_R1,T_R2,T_S1,T_S2,T_W1,T_W2,T_M1,T_M2};
  const int Ks[12]     = {128,128,256,256,256,256,256,256,256,256,256,256};
  const int Cos[12]    = {256,256,256,9,256,4,256,48,256,1,256,1};
  const float* Wp[12]  = {Wsp,Wst,Wp1,Wp2,Wr1,Wr2,Ws1,Ws2,Ww1,Ww2,Wm1,Wm2};
  int m = 0;
  #pragma unroll
  for (int i = 1; i < 12; ++i) if (b >= starts[i]) m = i;
  int local = b - starts[m];
  int KT = Ks[m] >> 4;
  int n0 = local / KT, k0 = local - n0 * KT;
  int col = n0 * 32 + (l & 31);
  int kbase = k0 * 16 + (l >> 5) * 8;
  const float* W = Wp[m];
  int Co = Cos[m];
  U4 pk;
  #pragma unroll
  for (int j = 0; j < 8; ++j) {
    float v = (col < Co) ? W[(size_t)(kbase + j) * Co + col] : 0.0f;
    pk.us[j] = f2bf(v);
  }
  ws[(size_t)b * 64 + l] = pk.u;
}

// ---- bulk copy of embeddings into output (non-indexed rows) ----
__global__ void copy_emb(const float4* pts, const float4* rot, const float4* h,
                         const float4* shs, float4* out) {
  long long stride = (long long)gridDim.x * blockDim.x;
  for (long long i = (long long)blockIdx.x * blockDim.x + threadIdx.x; i < 8400000LL; i += stride) {
    float4 v;
    if (i < 450000)        v = pts[i];
    else if (i < 1050000)  v = rot[i - 450000];
    else if (i < 1200000)  v = h[i - 1050000];
    else                   v = shs[i - 1200000];
    out[i] = v;
  }
}

// ---- fused MLP kernel: 64 rows/block, 8 waves, 13 phases ----
#define LSTR 512
__device__ __forceinline__ int lds_addr(int row, int cb) {
  return row * LSTR + (cb ^ ((row & 15) << 4));
}

__device__ __forceinline__ void loadX(const float* grid, int row0, int t, char* buf) {
  #pragma unroll
  for (int i = 0; i < 4; ++i) {
    int fi = i * 512 + t;
    int row = fi >> 5;
    int c4 = fi & 31;
    int gr = row0 + row; gr = gr < M_ROWS ? gr : (M_ROWS - 1);
    float4 v = ((const float4*)grid)[(size_t)gr * 32 + c4];
    ushort4 p;
    p.x = f2bf(v.x); p.y = f2bf(v.y); p.z = f2bf(v.z); p.w = f2bf(v.w);
    *(ushort4*)(buf + lds_addr(row, c4 * 8)) = p;
  }
}

__device__ __forceinline__ void pre8(U4 (&d)[8], const uint4* base, int lane) {
  #pragma unroll
  for (int i = 0; i < 8; ++i) d[i].u = base[(size_t)i * 64 + lane];
}
__device__ __forceinline__ void pre4(U4 (&d)[8], const uint4* base, int lane) {
  #pragma unroll
  for (int i = 0; i < 4; ++i) d[i].u = base[(size_t)i * 64 + lane];
}
__device__ __forceinline__ void pre_s2(U4 (&d)[8], const uint4* wt, int kq, int lane) {
  #pragma unroll
  for (int kk = 0; kk < 4; ++kk)
    #pragma unroll
    for (int n = 0; n < 2; ++n)
      d[kk * 2 + n].u = wt[(size_t)((n * 16 + kq * 4 + kk) * 64) + lane];
}

__device__ __forceinline__ void mm_big8(U4 (&b)[8], const char* inb, int k0, int arow, int khalf,
                                        f32x16& acc0, f32x16& acc1) {
  #pragma unroll
  for (int k = 0; k < 8; ++k) {
    bf16x8 a0 = *(const bf16x8*)(inb + lds_addr(arow, (k0 + k) * 32 + khalf));
    bf16x8 a1 = *(const bf16x8*)(inb + lds_addr(32 + arow, (k0 + k) * 32 + khalf));
    acc0 = __builtin_amdgcn_mfma_f32_32x32x16_bf16(a0, b[k].h, acc0, 0, 0, 0);
    acc1 = __builtin_amdgcn_mfma_f32_32x32x16_bf16(a1, b[k].h, acc1, 0, 0, 0);
  }
}

__device__ __forceinline__ void store_act(char* outb, const float* bias, int wave, int lane,
                                          const f32x16& acc0, const f32x16& acc1) {
  const int col = wave * 32 + (lane & 31);
  const float bv = bias[col];
  #pragma unroll
  for (int q = 0; q < 16; ++q) {
    int row = (q & 3) + 8 * (q >> 2) + 4 * (lane >> 5);
    float v0 = acc0[q] + bv; v0 = fmaxf(v0, 0.0f);
    float v1 = acc1[q] + bv; v1 = fmaxf(v1, 0.0f);
    *(unsigned short*)(outb + lds_addr(row, col * 2)) = f2bf(v0);
    *(unsigned short*)(outb + lds_addr(32 + row, col * 2)) = f2bf(v1);
  }
}

// head k-slice: 4 k-tiles, 2-acc ILP
__device__ __forceinline__ f32x16 mm_head1(U4 (&b)[8], const char* inb, int rg, int kq, int khalf,
                                           int lane) {
  const int arow = rg * 32 + (lane & 31);
  f32x16 hA = (f32x16)0.0f, hB = (f32x16)0.0f;
  bf16x8 a0 = *(const bf16x8*)(inb + lds_addr(arow, (kq * 4 + 0) * 32 + khalf));
  bf16x8 a1 = *(const bf16x8*)(inb + lds_addr(arow, (kq * 4 + 1) * 32 + khalf));
  bf16x8 a2 = *(const bf16x8*)(inb + lds_addr(arow, (kq * 4 + 2) * 32 + khalf));
  bf16x8 a3 = *(const bf16x8*)(inb + lds_addr(arow, (kq * 4 + 3) * 32 + khalf));
  hA = __builtin_amdgcn_mfma_f32_32x32x16_bf16(a0, b[0].h, hA, 0, 0, 0);
  hB = __builtin_amdgcn_mfma_f32_32x32x16_bf16(a1, b[1].h, hB, 0, 0, 0);
  hA = __builtin_amdgcn_mfma_f32_32x32x16_bf16(a2, b[2].h, hA, 0, 0, 0);
  hB = __builtin_amdgcn_mfma_f32_32x32x16_bf16(a3, b[3].h, hB, 0, 0, 0);
  return hA + hB;
}

__device__ __forceinline__ float red32(float v) {
  v += __shfl_xor(v, 1);  v += __shfl_xor(v, 2);  v += __shfl_xor(v, 4);
  v += __shfl_xor(v, 8);  v += __shfl_xor(v, 16);
  return v;
}

__global__ void __launch_bounds__(512, 4) deform_main(
    const float* grid_sp, const float* grid_st, const int* idx,
    const float* rays, const float* rotq, const float* shs_in,
    const float* time_emb, const float* h_emb,
    const uint4* ws, const float* Ww2f, const float* Wm2f,
    const float* b_sp, const float* b_st, const float* b_p1, const float* b_p2,
    const float* b_r1, const float* b_r2, const float* b_s1, const float* b_s2,
    const float* b_w1, const float* b_w2, const float* b_m1, const float* b_m2,
    float* out) {
  __shared__ char bufA[32768];
  __shared__ char bufB[32768];
  __shared__ float sm[3584];
  __shared__ int sidx[64];
  float* shsb = sm;          // [64*48]   P10-P12
  float* dxp  = sm;          // [4][64][9] P3-P6 (aliases shsb, disjoint in time)
  float* wp   = sm + 2304;   // [8][64]
  float* mup  = sm + 2816;   // [8][64]
  float* rotb = sm + 3328;   // [64*4]

  const int t = threadIdx.x;
  const int lane = t & 63;
  const int wave = t >> 6;
  const int rg = wave & 1;
  const int kq = wave >> 1;
  const int arow = lane & 31;
  const int khalf = (lane >> 5) * 16;
  const int row0 = blockIdx.x * 64;
  const float tt = time_emb[0];

  U4 b0[8], b1[8];
  pre8(b0, ws + (size_t)(T_SP + wave * 8) * 64, lane);

  // P0: idx hoist, zero rot accumulator, stage X_sp
  if (t < 64) { int gr = row0 + t; sidx[t] = idx[gr < M_ROWS ? gr : (M_ROWS - 1)]; }
  if (t < 256) rotb[t] = 0.0f;
  loadX(grid_sp, row0, t, bufA);
  __syncthreads();

  // P1: L_sp  bufA -> bufB (K=128)
  {
    f32x16 a0 = (f32x16)0.0f, a1 = (f32x16)0.0f;
    pre8(b1, ws + (size_t)(T_P1 + wave * 16) * 64, lane);
    __builtin_amdgcn_s_setprio(1);
    mm_big8(b0, bufA, 0, arow, khalf, a0, a1);
    __builtin_amdgcn_s_setprio(0);
    store_act(bufB, b_sp, wave, lane, a0, a1);
  }
  __syncthreads();

  // P2: L_p1  bufB -> bufA (K=256)
  {
    f32x16 a0 = (f32x16)0.0f, a1 = (f32x16)0.0f;
    pre8(b0, ws + (size_t)(T_P1 + wave * 16 + 8) * 64, lane);
    __builtin_amdgcn_s_setprio(1);
    mm_big8(b1, bufB, 0, arow, khalf, a0, a1);
    __builtin_amdgcn_s_setprio(0);
    pre4(b1, ws + (size_t)(T_P2 + kq * 4) * 64, lane);
    __builtin_amdgcn_s_setprio(1);
    mm_big8(b0, bufB, 8, arow, khalf, a0, a1);
    __builtin_amdgcn_s_setprio(0);
    store_act(bufA, b_p1, wave, lane, a0, a1);
  }
  __syncthreads();

  // P3: H_p2  dx partials (plain slot write, no atomics)
  {
    pre8(b0, ws + (size_t)(T_W1 + wave * 16) * 64, lane);
    f32x16 h = mm_head1(b1, bufA, rg, kq, khalf, lane);
    int col = lane & 31;
    if (col < 9) {
      #pragma unroll
      for (int q = 0; q < 16; ++q) {
        int row = rg * 32 + (q & 3) + 8 * (q >> 2) + 4 * (lane >> 5);
        dxp[(kq * 64 + row) * 9 + col] = h[q];
      }
    }
  }
  __syncthreads();

  // P4: fused w-branch: hidden col-slice in regs, relu, dot w2, shfl-reduce -> wp
  {
    f32x16 a0 = (f32x16)0.0f, a1 = (f32x16)0.0f;
    pre8(b1, ws + (size_t)(T_W1 + wave * 16 + 8) * 64, lane);
    __builtin_amdgcn_s_setprio(1);
    mm_big8(b0, bufB, 0, arow, khalf, a0, a1);
    __builtin_amdgcn_s_setprio(0);
    pre8(b0, ws + (size_t)(T_M1 + wave * 16) * 64, lane);
    __builtin_amdgcn_s_setprio(1);
    mm_big8(b1, bufB, 8, arow, khalf, a0, a1);
    __builtin_amdgcn_s_setprio(0);
    const int hcol = wave * 32 + (lane & 31);
    const float bv = b_w1[hcol], wv = Ww2f[hcol];
    #pragma unroll
    for (int q = 0; q < 16; ++q) {
      int row = (q & 3) + 8 * (q >> 2) + 4 * (lane >> 5);
      float s0 = red32(fmaxf(a0[q] + bv, 0.0f) * wv);
      float s1 = red32(fmaxf(a1[q] + bv, 0.0f) * wv);
      if ((lane & 31) == 0) { wp[wave * 64 + row] = s0; wp[wave * 64 + 32 + row] = s1; }
    }
  }
  __syncthreads();

  // P5: fused mu-branch -> mup ; issue pts/opac gather prefetch
  float pr = 0.0f, hv = 0.0f;
  {
    if (t < 256) {
      int row = t >> 2, sub = t & 3;
      int g = sidx[row];
      if (sub < 3) pr = rays[(size_t)g * 3 + sub]; else hv = h_emb[g];
    }
    f32x16 a0 = (f32x16)0.0f, a1 = (f32x16)0.0f;
    pre8(b1, ws + (size_t)(T_M1 + wave * 16 + 8) * 64, lane);
    __builtin_amdgcn_s_setprio(1);
    mm_big8(b0, bufB, 0, arow, khalf, a0, a1);
    __builtin_amdgcn_s_setprio(0);
    pre8(b0, ws + (size_t)(T_ST + wave * 8) * 64, lane);
    __builtin_amdgcn_s_setprio(1);
    mm_big8(b1, bufB, 8, arow, khalf, a0, a1);
    __builtin_amdgcn_s_setprio(0);
    const int hcol = wave * 32 + (lane & 31);
    const float bv = b_m1[hcol], wv = Wm2f[hcol];
    #pragma unroll
    for (int q = 0; q < 16; ++q) {
      int row = (q & 3) + 8 * (q >> 2) + 4 * (lane >> 5);
      float s0 = red32(fmaxf(a0[q] + bv, 0.0f) * wv);
      float s1 = red32(fmaxf(a1[q] + bv, 0.0f) * wv);
      if ((lane & 31) == 0) { mup[wave * 64 + row] = s0; mup[wave * 64 + 32 + row] = s1; }
    }
  }
  __syncthreads();

  // P6: stage X_st + pts/opacity epilogue
  loadX(grid_st, row0, t, bufA);
  if (t < 256) {
    int row = t >> 2, sub = t & 3;
    int gr = row0 + row;
    if (gr < M_ROWS) {
      int g = sidx[row];
      if (sub < 3) {
        float mt = 1.0f - tt;
        float c0 = 3.0f * mt * mt * tt, c1 = 3.0f * mt * tt * tt, c2 = tt * tt * tt;
        float d0 = b_p2[sub],     d1 = b_p2[3 + sub], d2 = b_p2[6 + sub];
        #pragma unroll
        for (int k = 0; k < 4; ++k) {
          const float* dp = &dxp[(k * 64 + row) * 9];
          d0 += dp[sub]; d1 += dp[3 + sub]; d2 += dp[6 + sub];
        }
        out[(size_t)g * 3 + sub] = pr + (c0 * d0 + c1 * d1 + c2 * d2);
      } else {
        float wr = b_w2[0], mr = b_m2[0];
        #pragma unroll
        for (int w8 = 0; w8 < 8; ++w8) { wr += wp[w8 * 64 + row]; mr += mup[w8 * 64 + row]; }
        float mu = 1.0f / (1.0f + expf(-mr));
        float dtm = tt - mu;
        out[4200000 + (size_t)g] = hv * expf(-(wr * wr) * dtm * dtm);
      }
    }
  }
  __syncthreads();

  // P7: L_st  bufA -> bufB (K=128)
  {
    f32x16 a0 = (f32x16)0.0f, a1 = (f32x16)0.0f;
    pre8(b1, ws + (size_t)(T_R1 + wave * 16) * 64, lane);
    __builtin_amdgcn_s_setprio(1);
    mm_big8(b0, bufA, 0, arow, khalf, a0, a1);
    __builtin_amdgcn_s_setprio(0);
    store_act(bufB, b_st, wave, lane, a0, a1);
  }
  __syncthreads();

  // P8: L_r1  bufB -> bufA
  {
    f32x16 a0 = (f32x16)0.0f, a1 = (f32x16)0.0f;
    pre8(b0, ws + (size_t)(T_R1 + wave * 16 + 8) * 64, lane);
    __builtin_amdgcn_s_setprio(1);
    mm_big8(b1, bufB, 0, arow, khalf, a0, a1);
    __builtin_amdgcn_s_setprio(0);
    pre4(b1, ws + (size_t)(T_R2 + kq * 4) * 64, lane);
    __builtin_amdgcn_s_setprio(1);
    mm_big8(b0, bufB, 8, arow, khalf, a0, a1);
    __builtin_amdgcn_s_setprio(0);
    store_act(bufA, b_r1, wave, lane, a0, a1);
  }
  __syncthreads();

  // P9: H_r2  rot head (atomic) ; issue rotq prefetch
  float4 rq;
  {
    if (t < 64) rq = ((const float4*)rotq)[sidx[t]];
    pre8(b0, ws + (size_t)(T_S1 + wave * 16) * 64, lane);
    f32x16 h = mm_head1(b1, bufA, rg, kq, khalf, lane);
    int col = lane & 31;
    if (col < 4) {
      #pragma unroll
      for (int q = 0; q < 16; ++q) {
        int row = rg * 32 + (q & 3) + 8 * (q >> 2) + 4 * (lane >> 5);
        atomicAdd(&rotb[row * 4 + col], h[q]);
      }
    }
  }
  __syncthreads();

  // P10: L_s1  bufB -> bufA ; rot epilogue ; zero shs accumulator
  {
    f32x16 a0 = (f32x16)0.0f, a1 = (f32x16)0.0f;
    pre8(b1, ws + (size_t)(T_S1 + wave * 16 + 8) * 64, lane);
    __builtin_amdgcn_s_setprio(1);
    mm_big8(b0, bufB, 0, arow, khalf, a0, a1);
    __builtin_amdgcn_s_setprio(0);
    pre_s2(b0, ws + (size_t)T_S2 * 64, kq, lane);
    __builtin_amdgcn_s_setprio(1);
    mm_big8(b1, bufB, 8, arow, khalf, a0, a1);
    __builtin_amdgcn_s_setprio(0);
    store_act(bufA, b_s1, wave, lane, a0, a1);
    #pragma unroll
    for (int i = 0; i < 6; ++i) shsb[i * 512 + t] = 0.0f;
    if (t < 64 && row0 + t < M_ROWS) {
      int g = sidx[t];
      float4 o;
      o.x = rq.x + rotb[t * 4 + 0] + b_r2[0];
      o.y = rq.y + rotb[t * 4 + 1] + b_r2[1];
      o.z = rq.z + rotb[t * 4 + 2] + b_r2[2];
      o.w = rq.w + rotb[t * 4 + 3] + b_r2[3];
      ((float4*)out)[450000 + (size_t)g] = o;
    }
  }
  __syncthreads();

  // P11: H_s2  shs head (atomic, 2 col-tiles) ; issue shs_in prefetch
  float4 sv0, sv1;
  int r0v = t / 12, c40 = t - r0v * 12;
  int e1 = 512 + t, r1v = e1 / 12, c41 = e1 - r1v * 12;
  {
    sv0 = ((const float4*)shs_in)[(size_t)sidx[r0v] * 12 + c40];
    if (t < 256) sv1 = ((const float4*)shs_in)[(size_t)sidx[r1v] * 12 + c41];
    f32x16 h0 = (f32x16)0.0f, h1 = (f32x16)0.0f;
    const int ar = rg * 32 + (lane & 31);
    #pragma unroll
    for (int kk = 0; kk < 4; ++kk) {
      bf16x8 a = *(const bf16x8*)(bufA + lds_addr(ar, (kq * 4 + kk) * 32 + khalf));
      h0 = __builtin_amdgcn_mfma_f32_32x32x16_bf16(a, b0[kk * 2 + 0].h, h0, 0, 0, 0);
      h1 = __builtin_amdgcn_mfma_f32_32x32x16_bf16(a, b0[kk * 2 + 1].h, h1, 0, 0, 0);
    }
    int c = lane & 31;
    #pragma unroll
    for (int q = 0; q < 16; ++q) {
      int row = rg * 32 + (q & 3) + 8 * (q >> 2) + 4 * (lane >> 5);
      atomicAdd(&shsb[row * 48 + c], h0[q]);
      if (c < 16) atomicAdd(&shsb[row * 48 + 32 + c], h1[q]);
    }
  }
  __syncthreads();

  // P12: shs epilogue (float4)
  {
    float4 bias0 = ((const float4*)b_s2)[c40];
    float4 acc0 = ((const float4*)shsb)[r0v * 12 + c40];
    if (row0 + r0v < M_ROWS) {
      float4 o;
      o.x = sv0.x + acc0.x + bias0.x; o.y = sv0.y + acc0.y + bias0.y;
      o.z = sv0.z + acc0.z + bias0.z; o.w = sv0.w + acc0.w + bias0.w;
      ((float4*)out)[1200000 + (size_t)sidx[r0v] * 12 + c40] = o;
    }
    if (t < 256) {
      float4 bias1 = ((const float4*)b_s2)[c41];
      float4 acc1 = ((const float4*)shsb)[r1v * 12 + c41];
      if (row0 + r1v < M_ROWS) {
        float4 o;
        o.x = sv1.x + acc1.x + bias1.x; o.y = sv1.y + acc1.y + bias1.y;
        o.z = sv1.z + acc1.z + bias1.z; o.w = sv1.w + acc1.w + bias1.w;
        ((float4*)out)[1200000 + (size_t)sidx[r1v] * 12 + c41] = o;
      }
    }
  }
}

extern "C" void kernel_launch(void* const* d_in, const int* in_sizes, int n_in,
                              void* d_out, int out_size, void* d_ws, size_t ws_size,
                              hipStream_t stream) {
  const float* rays     = (const float*)d_in[0];
  const float* rotq     = (const float*)d_in[1];
  const float* shs      = (const float*)d_in[2];
  const float* time_emb = (const float*)d_in[3];
  const float* h_emb    = (const float*)d_in[4];
  const float* grid_sp  = (const float*)d_in[5];
  const float* grid_st  = (const float*)d_in[6];
  const int*   idx      = (const int*)d_in[7];
  uint4* ws = (uint4*)d_ws;

  prep_w<<<T_TOT, 64, 0, stream>>>(
      (const float*)d_in[8],  (const float*)d_in[10], (const float*)d_in[12], (const float*)d_in[14],
      (const float*)d_in[16], (const float*)d_in[18], (const float*)d_in[20], (const float*)d_in[22],
      (const float*)d_in[24], (const float*)d_in[26], (const float*)d_in[28], (const float*)d_in[30],
      ws);

  copy_emb<<<2048, 256, 0, stream>>>((const float4*)rays, (const float4*)rotq,
                                     (const float4*)h_emb, (const float4*)shs, (float4*)d_out);

  deform_main<<<(M_ROWS + 63) / 64, 512, 0, stream>>>(
      grid_sp, grid_st, idx, rays, rotq, shs, time_emb, h_emb, ws,
      (const float*)d_in[26], (const float*)d_in[30],
      (const float*)d_in[9],  (const float*)d_in[11], (const float*)d_in[13], (const float*)d_in[15],
      (const float*)d_in[17], (const float*)d_in[19], (const float*)d_in[21], (const float*)d_in[23],
      (const float*)d_in[25], (const float*)d_in[27], (const float*)d_in[29], (const float*)d_in[31],
      (float*)d_out);
}